// Round 1
// baseline (848.842 us; speedup 1.0000x reference)
//
#include <hip/hip_runtime.h>
#include <cmath>

constexpr int IN_F  = 256;
constexpr int HEADS = 4;

// ---------------- GEMM (fp32, 64x64 tile, bounds-checked) ----------------
__global__ __launch_bounds__(256) void gemm_f32(
    const float* __restrict__ A, const float* __restrict__ B,
    const float* __restrict__ bias, float* __restrict__ C,
    int M, int N, int K)
{
    const int TS = 64, KS = 16;
    __shared__ float sA[64][17];   // [m][k], padded: conflict-free writes, broadcast reads
    __shared__ float sB[16][64];   // [k][n]
    int tid = threadIdx.x;
    int tx = tid & 15, ty = tid >> 4;
    int m0 = blockIdx.y * TS, n0 = blockIdx.x * TS;
    float acc[4][4] = {};
    for (int k0 = 0; k0 < K; k0 += KS) {
#pragma unroll
        for (int i = 0; i < 4; i++) {
            int idx = tid + i * 256;
            int mm = idx >> 4, kk = idx & 15;
            int gm = m0 + mm, gk = k0 + kk;
            sA[mm][kk] = (gm < M && gk < K) ? A[(size_t)gm * K + gk] : 0.f;
        }
#pragma unroll
        for (int i = 0; i < 4; i++) {
            int idx = tid + i * 256;
            int kk = idx >> 6, nn = idx & 63;
            int gk = k0 + kk, gn = n0 + nn;
            sB[kk][nn] = (gk < K && gn < N) ? B[(size_t)gk * N + gn] : 0.f;
        }
        __syncthreads();
#pragma unroll
        for (int kk = 0; kk < KS; kk++) {
            float ra[4], rb[4];
#pragma unroll
            for (int i = 0; i < 4; i++) ra[i] = sA[ty * 4 + i][kk];
#pragma unroll
            for (int j = 0; j < 4; j++) rb[j] = sB[kk][tx * 4 + j];
#pragma unroll
            for (int i = 0; i < 4; i++)
#pragma unroll
                for (int j = 0; j < 4; j++) acc[i][j] = fmaf(ra[i], rb[j], acc[i][j]);
        }
        __syncthreads();
    }
#pragma unroll
    for (int i = 0; i < 4; i++) {
        int gm = m0 + ty * 4 + i;
        if (gm >= M) continue;
#pragma unroll
        for (int j = 0; j < 4; j++) {
            int gn = n0 + tx * 4 + j;
            if (gn >= N) continue;
            float v = acc[i][j];
            if (bias) v += bias[gn];
            C[(size_t)gm * N + gn] = v;
        }
    }
}

// ---------------- el/er: layer 1 (C=4 heads, 512-dot per head) ----------------
__global__ __launch_bounds__(256) void el_er_1(
    const float* __restrict__ z, const float* __restrict__ al, const float* __restrict__ ar,
    float* __restrict__ el, float* __restrict__ er)
{
    int n = blockIdx.x;
    int wave = threadIdx.x >> 6, lane = threadIdx.x & 63;  // wave = head
    const float* zp  = z  + (size_t)n * 2048 + wave * 512;
    const float* alp = al + wave * 512;
    const float* arp = ar + wave * 512;
    float sl = 0.f, sr = 0.f;
    for (int k = lane; k < 512; k += 64) {
        float zv = zp[k];
        sl = fmaf(zv, alp[k], sl);
        sr = fmaf(zv, arp[k], sr);
    }
#pragma unroll
    for (int o = 32; o; o >>= 1) { sl += __shfl_down(sl, o); sr += __shfl_down(sr, o); }
    if (lane == 0) { el[n * 4 + wave] = sl; er[n * 4 + wave] = sr; }
}

// ---------------- el/er: layer 2 (C=16 = (p,h), 32-dot each) ----------------
__global__ void el_er_2(
    const float* __restrict__ z2, const float* __restrict__ al2, const float* __restrict__ ar2,
    float* __restrict__ el, float* __restrict__ er, int N)
{
    int idx = blockIdx.x * blockDim.x + threadIdx.x;  // N*16
    if (idx >= N * 16) return;
    int n = idx >> 4, c = idx & 15;
    int p = c >> 2, h = c & 3;
    const float* zp  = z2 + (size_t)n * 512 + p * 128 + h * 32;
    const float* alp = al2 + h * 32;
    const float* arp = ar2 + h * 32;
    float sl = 0.f, sr = 0.f;
#pragma unroll
    for (int k = 0; k < 32; k++) {
        float zv = zp[k];
        sl = fmaf(zv, alp[k], sl);
        sr = fmaf(zv, arp[k], sr);
    }
    el[idx] = sl;
    er[idx] = sr;
}

// ---------------- edge softmax helpers ----------------
__device__ __forceinline__ unsigned f2ord(float f) {
    unsigned u = __float_as_uint(f);
    return (u & 0x80000000u) ? ~u : (u | 0x80000000u);
}
__device__ __forceinline__ float ord2f(unsigned o) {
    unsigned u = (o & 0x80000000u) ? (o & 0x7FFFFFFFu) : ~o;
    return __uint_as_float(u);
}

template <int C>
__global__ void edge_logits(const int* __restrict__ src, const int* __restrict__ dst,
                            const float* __restrict__ el, const float* __restrict__ er,
                            float* __restrict__ ebuf, unsigned* __restrict__ emax, int E)
{
    int idx = blockIdx.x * blockDim.x + threadIdx.x;
    if (idx >= E * C) return;
    int e = idx / C, c = idx % C;
    float v = el[src[e] * C + c] + er[dst[e] * C + c];
    v = v > 0.f ? v : 0.2f * v;   // leaky_relu, slope 0.2
    ebuf[idx] = v;
    atomicMax(&emax[dst[e] * C + c], f2ord(v));
}

__global__ void finalize_max(const unsigned* __restrict__ emo, float* __restrict__ emf, int NC)
{
    int i = blockIdx.x * blockDim.x + threadIdx.x;
    if (i < NC) {
        float v = ord2f(emo[i]);
        emf[i] = isfinite(v) ? v : 0.f;
    }
}

template <int C>
__global__ void edge_exp(const int* __restrict__ dst, float* __restrict__ ebuf,
                         const float* __restrict__ emf, float* __restrict__ denom, int E)
{
    int idx = blockIdx.x * blockDim.x + threadIdx.x;
    if (idx >= E * C) return;
    int e = idx / C, c = idx % C;
    int d = dst[e];
    float ex = expf(ebuf[idx] - emf[d * C + c]);
    ebuf[idx] = ex;
    atomicAdd(&denom[d * C + c], ex);
}

// ---------------- CSR build (by dst) ----------------
__global__ void hist_kernel(const int* __restrict__ dst, int* __restrict__ deg, int E)
{
    int e = blockIdx.x * blockDim.x + threadIdx.x;
    if (e < E) atomicAdd(&deg[dst[e]], 1);
}

__global__ __launch_bounds__(1024) void scan_excl(const int* __restrict__ deg,
                                                  int* __restrict__ off, int N)
{
    __shared__ int part[1024];
    int t = threadIdx.x;
    int chunk = N >> 10;  // N/1024 (8 for N=8192)
    int base = t * chunk;
    int local[16];
    int s = 0;
    for (int i = 0; i < chunk; i++) { local[i] = s; s += deg[base + i]; }
    part[t] = s;
    __syncthreads();
    for (int o = 1; o < 1024; o <<= 1) {
        int v = (t >= o) ? part[t - o] : 0;
        __syncthreads();
        part[t] += v;
        __syncthreads();
    }
    int pre = (t == 0) ? 0 : part[t - 1];
    for (int i = 0; i < chunk; i++) off[base + i] = pre + local[i];
    if (t == 1023) off[N] = pre + s;
}

__global__ void scatter_kernel(const int* __restrict__ dst, const int* __restrict__ off,
                               int* __restrict__ cur, int* __restrict__ eid, int E)
{
    int e = blockIdx.x * blockDim.x + threadIdx.x;
    if (e < E) {
        int d = dst[e];
        int p = off[d] + atomicAdd(&cur[d], 1);
        eid[p] = e;
    }
}

// ---------------- aggregation: layer 1 (2048 f32 per node) ----------------
__global__ __launch_bounds__(256) void aggregate1(
    const int* __restrict__ off, const int* __restrict__ eid, const int* __restrict__ src,
    const float* __restrict__ ex, const float* __restrict__ denom,
    const float* __restrict__ z, float* __restrict__ acc)
{
    int n = blockIdx.x, t = threadIdx.x;
    float r[8] = {};
    int beg = off[n], end = off[n + 1];
    for (int j = beg; j < end; ++j) {
        int e = eid[j];
        const float* zs = z + (size_t)src[e] * 2048;
        float ah[4] = { ex[e * 4 + 0], ex[e * 4 + 1], ex[e * 4 + 2], ex[e * 4 + 3] };
#pragma unroll
        for (int i = 0; i < 8; ++i) {
            int col = i * 256 + t;
            r[i] = fmaf(ah[i >> 1], zs[col], r[i]);  // head = col/512 = i/2
        }
    }
#pragma unroll
    for (int i = 0; i < 8; ++i) {
        int col = i * 256 + t;
        float dn = denom[n * 4 + (i >> 1)];
        if (dn == 0.f) dn = 1.f;
        size_t o = (size_t)n * 2048 + col;
        float v = r[i] / dn + acc[o];
        acc[o] = v > 0.f ? v : 0.f;   // relu(rst + res + b)
    }
}

// ---------------- aggregation: layer 2 (512 f32 per node, C=16) ----------------
__global__ __launch_bounds__(256) void aggregate2(
    const int* __restrict__ off, const int* __restrict__ eid, const int* __restrict__ src,
    const float* __restrict__ ex, const float* __restrict__ denom,
    const float* __restrict__ z, float* __restrict__ acc)
{
    int n = blockIdx.x, t = threadIdx.x;
    float r[2] = {};
    int beg = off[n], end = off[n + 1];
    for (int j = beg; j < end; ++j) {
        int e = eid[j];
        const float* zs = z + (size_t)src[e] * 512;
#pragma unroll
        for (int i = 0; i < 2; ++i) {
            int col = i * 256 + t;
            r[i] = fmaf(ex[e * 16 + (col >> 5)], zs[col], r[i]);
        }
    }
#pragma unroll
    for (int i = 0; i < 2; ++i) {
        int col = i * 256 + t;
        float dn = denom[n * 16 + (col >> 5)];
        if (dn == 0.f) dn = 1.f;
        size_t o = (size_t)n * 512 + col;
        float v = r[i] / dn + acc[o];
        acc[o] = v > 0.f ? v : 0.f;
    }
}

// ---------------- launch ----------------
extern "C" void kernel_launch(void* const* d_in, const int* in_sizes, int n_in,
                              void* d_out, int out_size, void* d_ws, size_t ws_size,
                              hipStream_t stream)
{
    const float* feat  = (const float*)d_in[0];
    const int*   src   = (const int*)d_in[1];
    const int*   dst   = (const int*)d_in[2];
    const float* W1    = (const float*)d_in[3];
    const float* al1   = (const float*)d_in[4];
    const float* ar1   = (const float*)d_in[5];
    const float* resW1 = (const float*)d_in[6];
    const float* b1    = (const float*)d_in[7];
    const float* W2    = (const float*)d_in[8];
    const float* al2   = (const float*)d_in[9];
    const float* ar2   = (const float*)d_in[10];
    const float* resW2 = (const float*)d_in[11];
    const float* b2    = (const float*)d_in[12];
    const float* Wout  = (const float*)d_in[13];
    const float* bout  = (const float*)d_in[14];
    const int N = in_sizes[0] / IN_F;  // 8192
    const int E = in_sizes[1];         // 65536

    // ---- workspace layout ----
    char* w = (char*)d_ws;
    auto alloc = [&](size_t bytes) -> char* {
        char* p = w;
        w += (bytes + 255) & ~(size_t)255;
        return p;
    };
    float*    z1     = (float*)alloc((size_t)N * 2048 * 4);  // layer-2 buffers alias this region later
    float*    acc1   = (float*)alloc((size_t)N * 2048 * 4);  // res1+b1 -> h1 (in place)
    float*    el1    = (float*)alloc((size_t)N * 4 * 4);
    float*    er1    = (float*)alloc((size_t)N * 4 * 4);
    unsigned* emax1o = (unsigned*)alloc((size_t)N * 4 * 4);
    float*    emax1f = (float*)alloc((size_t)N * 4 * 4);
    float*    denom1 = (float*)alloc((size_t)N * 4 * 4);
    float*    e1     = (float*)alloc((size_t)E * 4 * 4);
    int*      deg    = (int*)alloc((size_t)N * 4);
    int*      off    = (int*)alloc((size_t)(N + 1) * 4);
    int*      cur    = (int*)alloc((size_t)N * 4);
    int*      eid    = (int*)alloc((size_t)E * 4);

    // layer-2 buffers alias z1's 67 MB region (z1 dead after aggregate1)
    char* w2 = (char*)z1;
    auto alloc2 = [&](size_t bytes) -> char* {
        char* p = w2;
        w2 += (bytes + 255) & ~(size_t)255;
        return p;
    };
    float*    z2     = (float*)alloc2((size_t)N * 512 * 4);
    float*    acc2   = (float*)alloc2((size_t)N * 512 * 4);  // res2+b2 -> h2 (in place)
    float*    el2    = (float*)alloc2((size_t)N * 16 * 4);
    float*    er2    = (float*)alloc2((size_t)N * 16 * 4);
    unsigned* emax2o = (unsigned*)alloc2((size_t)N * 16 * 4);
    float*    emax2f = (float*)alloc2((size_t)N * 16 * 4);
    float*    denom2 = (float*)alloc2((size_t)N * 16 * 4);
    float*    e2     = (float*)alloc2((size_t)E * 16 * 4);

    dim3 blk(256);

    // ===== CSR build (shared by both layers) =====
    hipMemsetAsync(deg, 0, (size_t)N * 4, stream);
    hipMemsetAsync(cur, 0, (size_t)N * 4, stream);
    hist_kernel<<<dim3((E + 255) / 256), blk, 0, stream>>>(dst, deg, E);
    scan_excl<<<dim3(1), dim3(1024), 0, stream>>>(deg, off, N);
    scatter_kernel<<<dim3((E + 255) / 256), blk, 0, stream>>>(dst, off, cur, eid, E);

    // ===== layer 1 =====
    // z1 = feat @ W1 ; acc1 = feat @ resW1 + b1
    gemm_f32<<<dim3(2048 / 64, N / 64), blk, 0, stream>>>(feat, W1, nullptr, z1, N, 2048, 256);
    gemm_f32<<<dim3(2048 / 64, N / 64), blk, 0, stream>>>(feat, resW1, b1, acc1, N, 2048, 256);
    el_er_1<<<dim3(N), blk, 0, stream>>>(z1, al1, ar1, el1, er1);

    hipMemsetAsync(emax1o, 0, (size_t)N * 4 * 4, stream);  // ord(0x0) acts as -inf/NaN identity
    hipMemsetAsync(denom1, 0, (size_t)N * 4 * 4, stream);
    edge_logits<4><<<dim3((E * 4 + 255) / 256), blk, 0, stream>>>(src, dst, el1, er1, e1, emax1o, E);
    finalize_max<<<dim3((N * 4 + 255) / 256), blk, 0, stream>>>(emax1o, emax1f, N * 4);
    edge_exp<4><<<dim3((E * 4 + 255) / 256), blk, 0, stream>>>(dst, e1, emax1f, denom1, E);
    aggregate1<<<dim3(N), blk, 0, stream>>>(off, eid, src, e1, denom1, z1, acc1);
    // acc1 now holds h1 [N,4,512]; z1 region is dead -> reused below

    // ===== layer 2 =====
    // z2 = h1 @ W2 ; acc2 = h1 @ resW2 + b2   (h1 viewed as [N*4, 512])
    gemm_f32<<<dim3(128 / 64, (N * 4) / 64), blk, 0, stream>>>(acc1, W2, nullptr, z2, N * 4, 128, 512);
    gemm_f32<<<dim3(128 / 64, (N * 4) / 64), blk, 0, stream>>>(acc1, resW2, b2, acc2, N * 4, 128, 512);
    el_er_2<<<dim3((N * 16 + 255) / 256), blk, 0, stream>>>(z2, al2, ar2, el2, er2, N);

    hipMemsetAsync(emax2o, 0, (size_t)N * 16 * 4, stream);
    hipMemsetAsync(denom2, 0, (size_t)N * 16 * 4, stream);
    edge_logits<16><<<dim3((E * 16 + 255) / 256), blk, 0, stream>>>(src, dst, el2, er2, e2, emax2o, E);
    finalize_max<<<dim3((N * 16 + 255) / 256), blk, 0, stream>>>(emax2o, emax2f, N * 16);
    edge_exp<16><<<dim3((E * 16 + 255) / 256), blk, 0, stream>>>(dst, e2, emax2f, denom2, E);
    aggregate2<<<dim3(N), blk, 0, stream>>>(off, eid, src, e2, denom2, z2, acc2);
    // acc2 now holds h2 [N,512]

    // ===== final linear: out = h2 @ Wout + bout =====
    gemm_f32<<<dim3(1, N / 64), blk, 0, stream>>>(acc2, Wout, bout, (float*)d_out, N, 40, 512);
}

// Round 2
// 405.580 us; speedup vs baseline: 2.0929x; 2.0929x over previous
//
#include <hip/hip_runtime.h>
#include <cmath>

constexpr int IN_F  = 256;

typedef short bf16x8 __attribute__((ext_vector_type(8)));
typedef short short4v __attribute__((ext_vector_type(4)));
typedef float f32x4 __attribute__((ext_vector_type(4)));

__device__ __forceinline__ short f2bf(float f) {
    unsigned u = __float_as_uint(f);
    unsigned r = (u + 0x7FFFu + ((u >> 16) & 1)) >> 16;  // RNE
    return (short)r;
}

// ---------------- fp32 -> bf16 flat conversion (vectorized) ----------------
__global__ void cvt_bf16(const float4* __restrict__ x, short4v* __restrict__ y, int n4)
{
    int i = blockIdx.x * blockDim.x + threadIdx.x;
    if (i < n4) {
        float4 v = x[i];
        short4v o;
        o[0] = f2bf(v.x); o[1] = f2bf(v.y); o[2] = f2bf(v.z); o[3] = f2bf(v.w);
        y[i] = o;
    }
}

// ---------------- fp32 W[K,N] -> bf16 Wt[N,K] (transpose) ----------------
__global__ __launch_bounds__(256) void cvt_t_bf16(
    const float* __restrict__ W, short* __restrict__ Wt, int K, int N)
{
    __shared__ float tile[32][33];
    int bk = blockIdx.y * 32, bn = blockIdx.x * 32;
    int tx = threadIdx.x & 31, ty = threadIdx.x >> 5;  // ty 0..7
#pragma unroll
    for (int i = ty; i < 32; i += 8) tile[i][tx] = W[(size_t)(bk + i) * N + bn + tx];
    __syncthreads();
#pragma unroll
    for (int i = ty; i < 32; i += 8)
        Wt[(size_t)(bn + i) * K + bk + tx] = f2bf(tile[tx][i]);
}

// ---------------- bf16 MFMA GEMM: A[M,K] x Bt[N,K]^T -> C[M,N] fp32 ----------------
// M%128==0, N%128==0, K%32==0. 128x128 tile, 4 waves (2x2 of 64x64), BK=32.
__global__ __launch_bounds__(256) void gemm_bf16(
    const short* __restrict__ A, const short* __restrict__ Bt,
    const float* __restrict__ bias, float* __restrict__ C,
    int M, int N, int K)
{
    __shared__ short sA[128 * 32];
    __shared__ short sB[128 * 32];
    const int tid  = threadIdx.x;
    const int wave = tid >> 6, lane = tid & 63;
    const int wm = wave >> 1, wn = wave & 1;
    const int m0 = blockIdx.y * 128, n0 = blockIdx.x * 128;

    const int srow = tid >> 2;          // 0..63 (tile row within 64-row half)
    const int scol = (tid & 3) * 8;     // element offset within K-tile

    const int fr = lane & 15;           // fragment row/col within 16
    const int fq = lane >> 4;           // k-quarter

    f32x4 acc[4][4] = {};

    for (int k0 = 0; k0 < K; k0 += 32) {
        const short* ga0 = A  + (size_t)(m0 + srow) * K + k0 + scol;
        const short* ga1 = A  + (size_t)(m0 + 64 + srow) * K + k0 + scol;
        const short* gb0 = Bt + (size_t)(n0 + srow) * K + k0 + scol;
        const short* gb1 = Bt + (size_t)(n0 + 64 + srow) * K + k0 + scol;
        // each wave-call moves 1024B: LDS base = wave*512 shorts (+2048 for second half)
        __builtin_amdgcn_global_load_lds((const __attribute__((address_space(1))) void*)ga0,
            (__attribute__((address_space(3))) void*)(sA + wave * 512), 16, 0, 0);
        __builtin_amdgcn_global_load_lds((const __attribute__((address_space(1))) void*)ga1,
            (__attribute__((address_space(3))) void*)(sA + 2048 + wave * 512), 16, 0, 0);
        __builtin_amdgcn_global_load_lds((const __attribute__((address_space(1))) void*)gb0,
            (__attribute__((address_space(3))) void*)(sB + wave * 512), 16, 0, 0);
        __builtin_amdgcn_global_load_lds((const __attribute__((address_space(1))) void*)gb1,
            (__attribute__((address_space(3))) void*)(sB + 2048 + wave * 512), 16, 0, 0);
        __syncthreads();

        bf16x8 af[4], bfr[4];
#pragma unroll
        for (int m = 0; m < 4; m++)
            af[m] = *(const bf16x8*)(sA + (wm * 64 + m * 16 + fr) * 32 + fq * 8);
#pragma unroll
        for (int n = 0; n < 4; n++)
            bfr[n] = *(const bf16x8*)(sB + (wn * 64 + n * 16 + fr) * 32 + fq * 8);
#pragma unroll
        for (int m = 0; m < 4; m++)
#pragma unroll
            for (int n = 0; n < 4; n++)
                acc[m][n] = __builtin_amdgcn_mfma_f32_16x16x32_bf16(af[m], bfr[n], acc[m][n], 0, 0, 0);
        __syncthreads();
    }

#pragma unroll
    for (int n = 0; n < 4; n++) {
        int gcol = n0 + wn * 64 + n * 16 + fr;
        float bv = bias ? bias[gcol] : 0.f;
#pragma unroll
        for (int m = 0; m < 4; m++) {
#pragma unroll
            for (int j = 0; j < 4; j++) {
                int grow = m0 + wm * 64 + m * 16 + fq * 4 + j;
                C[(size_t)grow * N + gcol] = acc[m][n][j] + bv;
            }
        }
    }
}

// ---------------- GEMM (fp32, 64x64 tile, bounds-checked) — final layer only ----------------
__global__ __launch_bounds__(256) void gemm_f32(
    const float* __restrict__ A, const float* __restrict__ B,
    const float* __restrict__ bias, float* __restrict__ C,
    int M, int N, int K)
{
    const int TS = 64, KS = 16;
    __shared__ float sA[64][17];
    __shared__ float sB[16][64];
    int tid = threadIdx.x;
    int tx = tid & 15, ty = tid >> 4;
    int m0 = blockIdx.y * TS, n0 = blockIdx.x * TS;
    float acc[4][4] = {};
    for (int k0 = 0; k0 < K; k0 += KS) {
#pragma unroll
        for (int i = 0; i < 4; i++) {
            int idx = tid + i * 256;
            int mm = idx >> 4, kk = idx & 15;
            int gm = m0 + mm, gk = k0 + kk;
            sA[mm][kk] = (gm < M && gk < K) ? A[(size_t)gm * K + gk] : 0.f;
        }
#pragma unroll
        for (int i = 0; i < 4; i++) {
            int idx = tid + i * 256;
            int kk = idx >> 6, nn = idx & 63;
            int gk = k0 + kk, gn = n0 + nn;
            sB[kk][nn] = (gk < K && gn < N) ? B[(size_t)gk * N + gn] : 0.f;
        }
        __syncthreads();
#pragma unroll
        for (int kk = 0; kk < KS; kk++) {
            float ra[4], rb[4];
#pragma unroll
            for (int i = 0; i < 4; i++) ra[i] = sA[ty * 4 + i][kk];
#pragma unroll
            for (int j = 0; j < 4; j++) rb[j] = sB[kk][tx * 4 + j];
#pragma unroll
            for (int i = 0; i < 4; i++)
#pragma unroll
                for (int j = 0; j < 4; j++) acc[i][j] = fmaf(ra[i], rb[j], acc[i][j]);
        }
        __syncthreads();
    }
#pragma unroll
    for (int i = 0; i < 4; i++) {
        int gm = m0 + ty * 4 + i;
        if (gm >= M) continue;
#pragma unroll
        for (int j = 0; j < 4; j++) {
            int gn = n0 + tx * 4 + j;
            if (gn >= N) continue;
            float v = acc[i][j];
            if (bias) v += bias[gn];
            C[(size_t)gm * N + gn] = v;
        }
    }
}

// ---------------- el/er: layer 1 (C=4 heads, 512-dot per head) ----------------
__global__ __launch_bounds__(256) void el_er_1(
    const float* __restrict__ z, const float* __restrict__ al, const float* __restrict__ ar,
    float* __restrict__ el, float* __restrict__ er)
{
    int n = blockIdx.x;
    int wave = threadIdx.x >> 6, lane = threadIdx.x & 63;  // wave = head
    const float* zp  = z  + (size_t)n * 2048 + wave * 512;
    const float* alp = al + wave * 512;
    const float* arp = ar + wave * 512;
    float sl = 0.f, sr = 0.f;
    for (int k = lane; k < 512; k += 64) {
        float zv = zp[k];
        sl = fmaf(zv, alp[k], sl);
        sr = fmaf(zv, arp[k], sr);
    }
#pragma unroll
    for (int o = 32; o; o >>= 1) { sl += __shfl_down(sl, o); sr += __shfl_down(sr, o); }
    if (lane == 0) { el[n * 4 + wave] = sl; er[n * 4 + wave] = sr; }
}

// ---------------- el/er: layer 2 (C=16 = (p,h), 32-dot each) ----------------
__global__ void el_er_2(
    const float* __restrict__ z2, const float* __restrict__ al2, const float* __restrict__ ar2,
    float* __restrict__ el, float* __restrict__ er, int N)
{
    int idx = blockIdx.x * blockDim.x + threadIdx.x;  // N*16
    if (idx >= N * 16) return;
    int n = idx >> 4, c = idx & 15;
    int p = c >> 2, h = c & 3;
    const float* zp  = z2 + (size_t)n * 512 + p * 128 + h * 32;
    const float* alp = al2 + h * 32;
    const float* arp = ar2 + h * 32;
    float sl = 0.f, sr = 0.f;
#pragma unroll
    for (int k = 0; k < 32; k++) {
        float zv = zp[k];
        sl = fmaf(zv, alp[k], sl);
        sr = fmaf(zv, arp[k], sr);
    }
    el[idx] = sl;
    er[idx] = sr;
}

// ---------------- edge softmax helpers ----------------
__device__ __forceinline__ unsigned f2ord(float f) {
    unsigned u = __float_as_uint(f);
    return (u & 0x80000000u) ? ~u : (u | 0x80000000u);
}
__device__ __forceinline__ float ord2f(unsigned o) {
    unsigned u = (o & 0x80000000u) ? (o & 0x7FFFFFFFu) : ~o;
    return __uint_as_float(u);
}

template <int C>
__global__ void edge_logits(const int* __restrict__ src, const int* __restrict__ dst,
                            const float* __restrict__ el, const float* __restrict__ er,
                            float* __restrict__ ebuf, unsigned* __restrict__ emax, int E)
{
    int idx = blockIdx.x * blockDim.x + threadIdx.x;
    if (idx >= E * C) return;
    int e = idx / C, c = idx % C;
    float v = el[src[e] * C + c] + er[dst[e] * C + c];
    v = v > 0.f ? v : 0.2f * v;   // leaky_relu, slope 0.2
    ebuf[idx] = v;
    atomicMax(&emax[dst[e] * C + c], f2ord(v));
}

__global__ void finalize_max(const unsigned* __restrict__ emo, float* __restrict__ emf, int NC)
{
    int i = blockIdx.x * blockDim.x + threadIdx.x;
    if (i < NC) {
        float v = ord2f(emo[i]);
        emf[i] = isfinite(v) ? v : 0.f;
    }
}

template <int C>
__global__ void edge_exp(const int* __restrict__ dst, float* __restrict__ ebuf,
                         const float* __restrict__ emf, float* __restrict__ denom, int E)
{
    int idx = blockIdx.x * blockDim.x + threadIdx.x;
    if (idx >= E * C) return;
    int e = idx / C, c = idx % C;
    int d = dst[e];
    float ex = expf(ebuf[idx] - emf[d * C + c]);
    ebuf[idx] = ex;
    atomicAdd(&denom[d * C + c], ex);
}

// ---------------- CSR build (by dst) ----------------
__global__ void hist_kernel(const int* __restrict__ dst, int* __restrict__ deg, int E)
{
    int e = blockIdx.x * blockDim.x + threadIdx.x;
    if (e < E) atomicAdd(&deg[dst[e]], 1);
}

__global__ __launch_bounds__(1024) void scan_excl(const int* __restrict__ deg,
                                                  int* __restrict__ off, int N)
{
    __shared__ int part[1024];
    int t = threadIdx.x;
    int chunk = N >> 10;
    int base = t * chunk;
    int local[16];
    int s = 0;
    for (int i = 0; i < chunk; i++) { local[i] = s; s += deg[base + i]; }
    part[t] = s;
    __syncthreads();
    for (int o = 1; o < 1024; o <<= 1) {
        int v = (t >= o) ? part[t - o] : 0;
        __syncthreads();
        part[t] += v;
        __syncthreads();
    }
    int pre = (t == 0) ? 0 : part[t - 1];
    for (int i = 0; i < chunk; i++) off[base + i] = pre + local[i];
    if (t == 1023) off[N] = pre + s;
}

__global__ void scatter_kernel(const int* __restrict__ dst, const int* __restrict__ off,
                               int* __restrict__ cur, int* __restrict__ eid, int E)
{
    int e = blockIdx.x * blockDim.x + threadIdx.x;
    if (e < E) {
        int d = dst[e];
        int p = off[d] + atomicAdd(&cur[d], 1);
        eid[p] = e;
    }
}

// ---------------- aggregation: layer 1 (2048 f32 per node) ----------------
__global__ __launch_bounds__(256) void aggregate1(
    const int* __restrict__ off, const int* __restrict__ eid, const int* __restrict__ src,
    const float* __restrict__ ex, const float* __restrict__ denom,
    const float* __restrict__ z, float* __restrict__ acc)
{
    int n = blockIdx.x, t = threadIdx.x;
    float r[8] = {};
    int beg = off[n], end = off[n + 1];
    for (int j = beg; j < end; ++j) {
        int e = eid[j];
        const float* zs = z + (size_t)src[e] * 2048;
        float ah[4] = { ex[e * 4 + 0], ex[e * 4 + 1], ex[e * 4 + 2], ex[e * 4 + 3] };
#pragma unroll
        for (int i = 0; i < 8; ++i) {
            int col = i * 256 + t;
            r[i] = fmaf(ah[i >> 1], zs[col], r[i]);
        }
    }
#pragma unroll
    for (int i = 0; i < 8; ++i) {
        int col = i * 256 + t;
        float dn = denom[n * 4 + (i >> 1)];
        if (dn == 0.f) dn = 1.f;
        size_t o = (size_t)n * 2048 + col;
        float v = r[i] / dn + acc[o];
        acc[o] = v > 0.f ? v : 0.f;
    }
}

// ---------------- aggregation: layer 2 (512 f32 per node, C=16) ----------------
__global__ __launch_bounds__(256) void aggregate2(
    const int* __restrict__ off, const int* __restrict__ eid, const int* __restrict__ src,
    const float* __restrict__ ex, const float* __restrict__ denom,
    const float* __restrict__ z, float* __restrict__ acc)
{
    int n = blockIdx.x, t = threadIdx.x;
    float r[2] = {};
    int beg = off[n], end = off[n + 1];
    for (int j = beg; j < end; ++j) {
        int e = eid[j];
        const float* zs = z + (size_t)src[e] * 512;
#pragma unroll
        for (int i = 0; i < 2; ++i) {
            int col = i * 256 + t;
            r[i] = fmaf(ex[e * 16 + (col >> 5)], zs[col], r[i]);
        }
    }
#pragma unroll
    for (int i = 0; i < 2; ++i) {
        int col = i * 256 + t;
        float dn = denom[n * 16 + (col >> 5)];
        if (dn == 0.f) dn = 1.f;
        size_t o = (size_t)n * 512 + col;
        float v = r[i] / dn + acc[o];
        acc[o] = v > 0.f ? v : 0.f;
    }
}

// ---------------- launch ----------------
extern "C" void kernel_launch(void* const* d_in, const int* in_sizes, int n_in,
                              void* d_out, int out_size, void* d_ws, size_t ws_size,
                              hipStream_t stream)
{
    const float* feat  = (const float*)d_in[0];
    const int*   src   = (const int*)d_in[1];
    const int*   dst   = (const int*)d_in[2];
    const float* W1    = (const float*)d_in[3];
    const float* al1   = (const float*)d_in[4];
    const float* ar1   = (const float*)d_in[5];
    const float* resW1 = (const float*)d_in[6];
    const float* b1    = (const float*)d_in[7];
    const float* W2    = (const float*)d_in[8];
    const float* al2   = (const float*)d_in[9];
    const float* ar2   = (const float*)d_in[10];
    const float* resW2 = (const float*)d_in[11];
    const float* b2    = (const float*)d_in[12];
    const float* Wout  = (const float*)d_in[13];
    const float* bout  = (const float*)d_in[14];
    const int N = in_sizes[0] / IN_F;  // 8192
    const int E = in_sizes[1];         // 65536

    // ---- workspace layout ----
    char* w = (char*)d_ws;
    auto alloc = [&](size_t bytes) -> char* {
        char* p = w;
        w += (bytes + 255) & ~(size_t)255;
        return p;
    };
    float*    z1      = (float*)alloc((size_t)N * 2048 * 4);  // region A (64 MB)
    float*    acc1    = (float*)alloc((size_t)N * 2048 * 4);  // region B (64 MB)
    float*    el1     = (float*)alloc((size_t)N * 4 * 4);
    float*    er1     = (float*)alloc((size_t)N * 4 * 4);
    unsigned* emax1o  = (unsigned*)alloc((size_t)N * 4 * 4);
    float*    emax1f  = (float*)alloc((size_t)N * 4 * 4);
    float*    denom1  = (float*)alloc((size_t)N * 4 * 4);
    float*    e1      = (float*)alloc((size_t)E * 4 * 4);
    int*      deg     = (int*)alloc((size_t)N * 4);
    int*      off     = (int*)alloc((size_t)(N + 1) * 4);
    int*      cur     = (int*)alloc((size_t)N * 4);
    int*      eid     = (int*)alloc((size_t)E * 4);
    short*    featb   = (short*)alloc((size_t)N * 256 * 2);   // 4 MB
    short*    W1t     = (short*)alloc((size_t)2048 * 256 * 2);
    short*    resW1t  = (short*)alloc((size_t)2048 * 256 * 2);
    short*    W2t     = (short*)alloc((size_t)128 * 512 * 2);
    short*    resW2t  = (short*)alloc((size_t)128 * 512 * 2);

    // region A alias: h1b (written after z1 is dead)
    short* h1b = (short*)z1;                                  // 32 MB < 64 MB
    // region B alias: layer-2 buffers (acc1/h1-fp32 dead after cvt to h1b)
    char* w2 = (char*)acc1;
    auto alloc2 = [&](size_t bytes) -> char* {
        char* p = w2;
        w2 += (bytes + 255) & ~(size_t)255;
        return p;
    };
    float*    z2     = (float*)alloc2((size_t)N * 512 * 4);   // 16 MB
    float*    acc2   = (float*)alloc2((size_t)N * 512 * 4);   // 16 MB
    float*    el2    = (float*)alloc2((size_t)N * 16 * 4);
    float*    er2    = (float*)alloc2((size_t)N * 16 * 4);
    unsigned* emax2o = (unsigned*)alloc2((size_t)N * 16 * 4);
    float*    emax2f = (float*)alloc2((size_t)N * 16 * 4);
    float*    denom2 = (float*)alloc2((size_t)N * 16 * 4);
    float*    e2     = (float*)alloc2((size_t)E * 16 * 4);    // 4 MB (total ~39 MB < 64 MB)

    dim3 blk(256);

    // ===== CSR build =====
    hipMemsetAsync(deg, 0, (size_t)N * 4, stream);
    hipMemsetAsync(cur, 0, (size_t)N * 4, stream);
    hist_kernel<<<dim3((E + 255) / 256), blk, 0, stream>>>(dst, deg, E);
    scan_excl<<<dim3(1), dim3(1024), 0, stream>>>(deg, off, N);
    scatter_kernel<<<dim3((E + 255) / 256), blk, 0, stream>>>(dst, off, cur, eid, E);

    // ===== weight/feature conversion to bf16 (weights transposed to [N,K]) =====
    cvt_bf16<<<dim3((N * 256 / 4 + 255) / 256), blk, 0, stream>>>((const float4*)feat, (short4v*)featb, N * 256 / 4);
    cvt_t_bf16<<<dim3(2048 / 32, 256 / 32), blk, 0, stream>>>(W1, W1t, 256, 2048);
    cvt_t_bf16<<<dim3(2048 / 32, 256 / 32), blk, 0, stream>>>(resW1, resW1t, 256, 2048);
    cvt_t_bf16<<<dim3(128 / 32, 512 / 32), blk, 0, stream>>>(W2, W2t, 512, 128);
    cvt_t_bf16<<<dim3(128 / 32, 512 / 32), blk, 0, stream>>>(resW2, resW2t, 512, 128);

    // ===== layer 1 (MFMA) =====
    gemm_bf16<<<dim3(2048 / 128, N / 128), blk, 0, stream>>>(featb, W1t, nullptr, z1, N, 2048, 256);
    gemm_bf16<<<dim3(2048 / 128, N / 128), blk, 0, stream>>>(featb, resW1t, b1, acc1, N, 2048, 256);
    el_er_1<<<dim3(N), blk, 0, stream>>>(z1, al1, ar1, el1, er1);

    hipMemsetAsync(emax1o, 0, (size_t)N * 4 * 4, stream);
    hipMemsetAsync(denom1, 0, (size_t)N * 4 * 4, stream);
    edge_logits<4><<<dim3((E * 4 + 255) / 256), blk, 0, stream>>>(src, dst, el1, er1, e1, emax1o, E);
    finalize_max<<<dim3((N * 4 + 255) / 256), blk, 0, stream>>>(emax1o, emax1f, N * 4);
    edge_exp<4><<<dim3((E * 4 + 255) / 256), blk, 0, stream>>>(dst, e1, emax1f, denom1, E);
    aggregate1<<<dim3(N), blk, 0, stream>>>(off, eid, src, e1, denom1, z1, acc1);
    // acc1 = h1 fp32 ; z1 dead

    // h1 -> bf16 (into region A)
    cvt_bf16<<<dim3((N * 2048 / 4 + 255) / 256), blk, 0, stream>>>((const float4*)acc1, (short4v*)h1b, N * 2048 / 4);
    // acc1 (fp32 h1) now dead -> region B reused for layer-2 buffers

    // ===== layer 2 (MFMA) =====
    gemm_bf16<<<dim3(128 / 128, (N * 4) / 128), blk, 0, stream>>>(h1b, W2t, nullptr, z2, N * 4, 128, 512);
    gemm_bf16<<<dim3(128 / 128, (N * 4) / 128), blk, 0, stream>>>(h1b, resW2t, b2, acc2, N * 4, 128, 512);
    el_er_2<<<dim3((N * 16 + 255) / 256), blk, 0, stream>>>(z2, al2, ar2, el2, er2, N);

    hipMemsetAsync(emax2o, 0, (size_t)N * 16 * 4, stream);
    hipMemsetAsync(denom2, 0, (size_t)N * 16 * 4, stream);
    edge_logits<16><<<dim3((E * 16 + 255) / 256), blk, 0, stream>>>(src, dst, el2, er2, e2, emax2o, E);
    finalize_max<<<dim3((N * 16 + 255) / 256), blk, 0, stream>>>(emax2o, emax2f, N * 16);
    edge_exp<16><<<dim3((E * 16 + 255) / 256), blk, 0, stream>>>(dst, e2, emax2f, denom2, E);
    aggregate2<<<dim3(N), blk, 0, stream>>>(off, eid, src, e2, denom2, z2, acc2);
    // acc2 = h2 fp32

    // ===== final linear (fp32): out = h2 @ Wout + bout =====
    gemm_f32<<<dim3(1, N / 64), blk, 0, stream>>>(acc2, Wout, bout, (float*)d_out, N, 40, 512);
}